// Round 6
// baseline (205.861 us; speedup 1.0000x reference)
//
#include <hip/hip_runtime.h>
#include <hip/hip_bf16.h>
#include <math.h>

#define B_N 8192
#define E_N 512
#define T_N 32
#define BP 520  // B LDS pitch in shorts (1040 B, 16B-aligned rows)

typedef short bf16x8 __attribute__((ext_vector_type(8)));
typedef float f32x4 __attribute__((ext_vector_type(4)));

// ---------------- ws layout (bytes) ----------------
#define WS_CNT    128      // main: last-block counter (zeroed by k_prep_cvt)
#define WS_OFFS   256      // offs[33] (both paths)
#define WS_RANK   512      // fallback
#define WS_ORDER  33280    // order[8192] (both paths)
#define WS_YACC   66048    // fallback
#define WS_YACC8  98816    // main: 8 x 8192 floats (256 KB), slab = nt
#define WS_GA     (WS_YACC8 + 8 * B_N * 4)          // bf16 copy of g_exp (8.4 MB)
#define WS_REQ    (WS_GA + (size_t)B_N * E_N * 2)

static __device__ __forceinline__ unsigned short f2bf(float f) {
    unsigned int u = __float_as_uint(f);
    unsigned int r = u + 0x7fffu + ((u >> 16) & 1u);  // RNE
    return (unsigned short)(r >> 16);
}

// packed f32x2 -> bf16x2 (RNE)
static __device__ __forceinline__ unsigned int pk2(float a, float b) {
    __hip_bfloat162 h = __float22bfloat162_rn(float2{a, b});
    unsigned int u;
    __builtin_memcpy(&u, &h, 4);
    return u;
}

// ---- prep: blocks 0..2047 convert g_exp f32->bf16; block 2048 builds the
// tissue counting-sort (offs/order) ONCE and zeroes the finish counter.
// v12 post-mortem: every gemm block redid the full-tv sort (100% redundant,
// serial prologue); hoisted here where it hides under the cvt streaming.
__global__ __launch_bounds__(256) void k_prep_cvt(
    const float* __restrict__ g_exp, unsigned short* __restrict__ gA,
    const int* __restrict__ tv, int* __restrict__ offs_g,
    int* __restrict__ order, int* __restrict__ cnt) {
    int blk = blockIdx.x;
    int tid = threadIdx.x;
    if (blk < 2048) {  // cvt: 8 floats per thread
        int i = blk * 256 + tid;
        const f32x4* src = (const f32x4*)g_exp + (size_t)i * 2;
        f32x4 a = src[0], b = src[1];
        unsigned int uu[4] = {pk2(a[0], a[1]), pk2(a[2], a[3]),
                              pk2(b[0], b[1]), pk2(b[2], b[3])};
        int4 v;
        __builtin_memcpy(&v, uu, 16);
        *(int4*)(gA + (size_t)i * 8) = v;
        return;
    }
    // ---- single-block counting sort (proven k_prep_sb structure) ----
    __shared__ int lh[4][32], wcur[4][32], offs_s[33];
    int w = tid >> 6;
    if (tid < 128) lh[tid >> 5][tid & 31] = 0;
    __syncthreads();
    int tval[32];
#pragma unroll
    for (int c = 0; c < 32; ++c) tval[c] = tv[c * 256 + tid];
#pragma unroll
    for (int c = 0; c < 32; ++c) atomicAdd(&lh[w][tval[c]], 1);
    __syncthreads();
    if (tid < 32) {
        int s = lh[0][tid] + lh[1][tid] + lh[2][tid] + lh[3][tid];
        int excl = 0;
#pragma unroll
        for (int i = 0; i < 32; ++i) {
            int v = __shfl(s, i, 64);
            if (i < tid) excl += v;
        }
        offs_s[tid] = excl;
        offs_g[tid] = excl;
        if (tid == 31) { offs_s[32] = excl + s; offs_g[32] = excl + s; }
    }
    __syncthreads();
    if (tid < 128) {
        int ww = tid >> 5, t = tid & 31;
        int s = offs_s[t];
        for (int w2 = 0; w2 < ww; ++w2) s += lh[w2][t];
        wcur[ww][t] = s;
    }
    __syncthreads();
#pragma unroll
    for (int c = 0; c < 32; ++c) {
        int b = c * 256 + tid;
        int pos = atomicAdd(&wcur[w][tval[c]], 1);
        order[pos] = b;
    }
    if (tid == 0) *cnt = 0;
}

// ---------- fused GEMM v13: (tissue, 64-col slice, row-half) blocks.
// Changes vs v12: (1) sort hoisted to k_prep_cvt -- gemm prologue is now
// just the B pack (no 32KB tv scan per block); (2) final softplus
// reduction fused via last-block pattern (threadfence + atomicAdd) --
// one fewer dispatch+gap. Compute core unchanged from verified v12:
// bf16 A global->VGPR depth-4 named ring, XOR-swizzled bf16 B in LDS,
// no main-loop barriers, 2 blocks/CU. wi%8 == t%8 keeps a tissue's 16
// blocks on one XCD (L2 reuse of A rows + shared W1 slice).
__global__ __launch_bounds__(512, 4) void k_gemm_mfma(
    const unsigned short* __restrict__ gA, const float* __restrict__ W1,
    const int* __restrict__ offs, const int* __restrict__ order,
    const float* __restrict__ b1, const float* __restrict__ W2,
    float* __restrict__ yacc8, int* __restrict__ cnt,
    const int* __restrict__ tv, const float* __restrict__ b2,
    float* __restrict__ out) {
    int wi = blockIdx.x;
    int t = wi & 31, nt = (wi >> 5) & 7, h = wi >> 8;
    int n0 = nt * 64;

    int tid = threadIdx.x;
    int w = tid >> 6, lane = tid & 63;
    int quad = (lane >> 4) & 3, l15 = lane & 15;

    __shared__ __align__(16) unsigned short Bs[64 * BP];  // 66560 B

    int base = offs[t];
    int n_t = offs[t + 1] - base;

    // per-lane epilogue constants (cols n0 + ni*16 + l15)
    float b1v[4], w2v[4];
#pragma unroll
    for (int ni = 0; ni < 4; ++ni) {
        int n = t * E_N + n0 + ni * 16 + l15;
        b1v[ni] = b1[n];
        w2v[ni] = W2[n];
    }

    // ---- B prologue: W1[t][k][n0:n0+64] fp32 -> Bs[n][k] bf16 (k-major,
    // packed pairs, word idx XOR-swizzled). Two-phase x2: batch 4 iters'
    // loads (8 in flight), then pack+write -- overlaps cold-HBM latency.
    const float* Wsrc = W1 + (size_t)t * E_N * E_N + n0;
    unsigned int* Bw = (unsigned int*)Bs;  // word idx = n*260 + swz(k2)
#pragma unroll 1
    for (int g = 0; g < 2; ++g) {
        float4 va[4], vb[4];
#pragma unroll
        for (int i = 0; i < 4; ++i) {
            int flat = (g * 4 + i) * 512 + tid;  // 0..4095
            int k2 = flat >> 4, nq = flat & 15;
            va[i] = *(const float4*)(Wsrc + (size_t)(2 * k2) * E_N + nq * 4);
            vb[i] = *(const float4*)(Wsrc + (size_t)(2 * k2 + 1) * E_N + nq * 4);
        }
#pragma unroll
        for (int i = 0; i < 4; ++i) {
            int flat = (g * 4 + i) * 512 + tid;
            int k2 = flat >> 4, nq = flat & 15;
            int k2s = k2 ^ ((nq & 7) << 2);  // matches read swizzle ((n>>2)&7)<<2
            Bw[(nq * 4 + 0) * 260 + k2s] = pk2(va[i].x, vb[i].x);
            Bw[(nq * 4 + 1) * 260 + k2s] = pk2(va[i].y, vb[i].y);
            Bw[(nq * 4 + 2) * 260 + k2s] = pk2(va[i].z, vb[i].z);
            Bw[(nq * 4 + 3) * 260 + k2s] = pk2(va[i].w, vb[i].w);
        }
    }
    __syncthreads();  // Bs final -- the ONLY barrier before the finish protocol

    int MCn = (n_t + 127) >> 7;        // total 128-row chunks for this tissue
    int MC = (MCn + 1 - h) >> 1;       // chunks of parity h owned by this block

    float* slab = yacc8 + (size_t)nt * B_N;

    for (int mc = 0; mc < MC; ++mc) {
        // lane (quad,l15): A-frag = 8 consecutive bf16 k-values of its row
        int ridx = (2 * mc + h) * 128 + w * 16 + l15;
        int row = order[base + (ridx < n_t ? ridx : 0)];
        const bf16x8* pAb = (const bf16x8*)(gA + (size_t)row * E_N) + quad;  // [ks*4]

        f32x4 acc[4];
#pragma unroll
        for (int ni = 0; ni < 4; ++ni) acc[ni] = (f32x4){0.f, 0.f, 0.f, 0.f};

        // depth-4 ring: named buffers, no register copies
        bf16x8 A0 = pAb[0], A1 = pAb[4], A2 = pAb[8], A3 = pAb[12];

#define KSTEP(S, ks) do {                                                                   \
        bf16x8 af = A##S;                                                                   \
        if (k4 < 3) A##S = pAb[((ks) + 4) * 4];                                             \
        _Pragma("unroll") for (int ni = 0; ni < 4; ++ni) {                                  \
            int bswz = ((ni * 4 + (l15 >> 2)) & 7) << 3;  /* read-side XOR (shorts) */      \
            bf16x8 bfr = *(const bf16x8*)(Bs + (ni * 16 + l15) * BP +                       \
                                          (((ks) * 32 + quad * 8) ^ bswz));                 \
            acc[ni] = __builtin_amdgcn_mfma_f32_16x16x32_bf16(af, bfr, acc[ni], 0, 0, 0);   \
        }                                                                                   \
    } while (0)

#pragma unroll 1
        for (int k4 = 0; k4 < 4; ++k4) {
            int ksb = k4 * 4;
            KSTEP(0, ksb + 0);
            KSTEP(1, ksb + 1);
            KSTEP(2, ksb + 2);
            KSTEP(3, ksb + 3);
        }
#undef KSTEP

        // epilogue: gelu(acc + b1) * W2, dot over this block's 64 cols
        float pr[4] = {0.f, 0.f, 0.f, 0.f};
#pragma unroll
        for (int ni = 0; ni < 4; ++ni) {
#pragma unroll
            for (int r = 0; r < 4; ++r) {
                float u = acc[ni][r] + b1v[ni];
                float gg = 0.5f * u * (1.f + erff(u * 0.70710678118654752f));
                pr[r] = fmaf(gg, w2v[ni], pr[r]);
            }
        }
#pragma unroll
        for (int off = 1; off <= 8; off <<= 1)
#pragma unroll
            for (int r = 0; r < 4; ++r) pr[r] += __shfl_xor(pr[r], off, 64);

        if (l15 == 0) {
#pragma unroll
            for (int r = 0; r < 4; ++r) {
                int rr = (2 * mc + h) * 128 + w * 16 + quad * 4 + r;  // global rank
                if (rr < n_t) slab[order[base + rr]] = pr[r];
            }
        }
    }

    // ---- fused final: last block to finish sums the 8 slabs + softplus ----
    __threadfence();                        // release my slab stores (device scope)
    __syncthreads();
    __shared__ int lastf;
    if (tid == 0) lastf = (atomicAdd(cnt, 1) == (int)gridDim.x - 1);
    __syncthreads();
    if (lastf) {
        __threadfence();                    // acquire all blocks' slab stores
        for (int i = tid; i < B_N; i += 512) {
            float x = b2[tv[i]];
#pragma unroll
            for (int s = 0; s < 8; ++s) x += yacc8[(size_t)s * B_N + i];
            out[i] = fmaxf(x, 0.f) + log1pf(expf(-fabsf(x)));  // stable softplus
        }
    }
}

// ================= fallback (fp32 path, proven) =================
__global__ __launch_bounds__(256) void k_prep_sb(
    const int* __restrict__ tv, int* __restrict__ offs_g,
    int* __restrict__ rank, int* __restrict__ order, float* __restrict__ yacc) {
    __shared__ int lh[4][32], wcur[4][32], offs_s[33];
    int tid = threadIdx.x, w = tid >> 6;
    if (tid < 128) lh[tid >> 5][tid & 31] = 0;
    __syncthreads();
    int tval[32];
#pragma unroll
    for (int c = 0; c < 32; ++c) tval[c] = tv[c * 256 + tid];
#pragma unroll
    for (int c = 0; c < 32; ++c) atomicAdd(&lh[w][tval[c]], 1);
    __syncthreads();
    if (tid < 32) {
        int s = lh[0][tid] + lh[1][tid] + lh[2][tid] + lh[3][tid];
        int excl = 0;
#pragma unroll
        for (int i = 0; i < 32; ++i) {
            int v = __shfl(s, i, 64);
            if (i < tid) excl += v;
        }
        offs_s[tid] = excl;
        offs_g[tid] = excl;
        if (tid == 31) { offs_s[32] = excl + s; offs_g[32] = excl + s; }
    }
    __syncthreads();
    if (tid < 128) {
        int ww = tid >> 5, t = tid & 31;
        int s = offs_s[t];
        for (int w2 = 0; w2 < ww; ++w2) s += lh[w2][t];
        wcur[ww][t] = s;
    }
    __syncthreads();
#pragma unroll
    for (int c = 0; c < 32; ++c) {
        int b = c * 256 + tid;
        int pos = atomicAdd(&wcur[w][tval[c]], 1);
        rank[b] = pos;
        order[pos] = b;
    }
    float4 z = make_float4(0.f, 0.f, 0.f, 0.f);
#pragma unroll
    for (int c = 0; c < 8; ++c) *(float4*)(yacc + (c * 256 + tid) * 4) = z;
}

__global__ __launch_bounds__(256) void fb_gemm(
    const float* __restrict__ g_exp, const float* __restrict__ W1,
    const float* __restrict__ b1, const float* __restrict__ W2,
    const int* __restrict__ offs, const int* __restrict__ order,
    float* __restrict__ yacc) {
    int t = blockIdx.z;
    int base = offs[t];
    int n_t = offs[t + 1] - base;
    int m0 = blockIdx.y * 64;
    if (m0 >= n_t) return;
    int n0 = blockIdx.x * 128;

    __shared__ float As2[32][68];
    __shared__ float Bs2[32][128];
    __shared__ int sidx[64];

    int tid = threadIdx.x;
    if (tid < 64) {
        int m = m0 + tid;
        sidx[tid] = (m < n_t) ? order[base + m] : -1;
    }
    __syncthreads();

    int ty = tid >> 4, tx = tid & 15;
    float acc[4][8];
#pragma unroll
    for (int r = 0; r < 4; ++r)
#pragma unroll
        for (int c = 0; c < 8; ++c) acc[r][c] = 0.f;

    for (int k0 = 0; k0 < E_N; k0 += 32) {
#pragma unroll
        for (int p = 0; p < 2; ++p) {
            int idx = tid + 256 * p;
            int row = idx >> 3, kcq = idx & 7;
            int s = sidx[row];
            float4 v = make_float4(0.f, 0.f, 0.f, 0.f);
            if (s >= 0) v = *(const float4*)(g_exp + (size_t)s * E_N + k0 + kcq * 4);
            As2[kcq * 4 + 0][row] = v.x;
            As2[kcq * 4 + 1][row] = v.y;
            As2[kcq * 4 + 2][row] = v.z;
            As2[kcq * 4 + 3][row] = v.w;
        }
#pragma unroll
        for (int p = 0; p < 4; ++p) {
            int idx = tid + 256 * p;
            int kr = idx >> 5, c4 = idx & 31;
            *(float4*)(&Bs2[kr][c4 * 4]) =
                *(const float4*)(W1 + ((size_t)t * E_N + (k0 + kr)) * E_N + n0 + c4 * 4);
        }
        __syncthreads();
#pragma unroll
        for (int e = 0; e < 32; ++e) {
            float4 a = *(const float4*)(&As2[e][ty * 4]);
            float4 bA = *(const float4*)(&Bs2[e][tx * 4]);
            float4 bB = *(const float4*)(&Bs2[e][tx * 4 + 64]);
            float av[4] = {a.x, a.y, a.z, a.w};
            float bv[8] = {bA.x, bA.y, bA.z, bA.w, bB.x, bB.y, bB.z, bB.w};
#pragma unroll
            for (int r = 0; r < 4; ++r)
#pragma unroll
                for (int c = 0; c < 8; ++c) acc[r][c] = fmaf(av[r], bv[c], acc[r][c]);
        }
        __syncthreads();
    }

    float pr[4] = {0.f, 0.f, 0.f, 0.f};
#pragma unroll
    for (int c = 0; c < 8; ++c) {
        int n = n0 + tx * 4 + ((c >= 4) ? 64 : 0) + (c & 3);
        float bb = b1[t * E_N + n];
        float w2 = W2[t * E_N + n];
#pragma unroll
        for (int r = 0; r < 4; ++r) {
            float u = acc[r][c] + bb;
            float g = 0.5f * u * (1.f + erff(u * 0.70710678118654752f));
            pr[r] = fmaf(g, w2, pr[r]);
        }
    }
#pragma unroll
    for (int off = 8; off >= 1; off >>= 1)
#pragma unroll
        for (int r = 0; r < 4; ++r) pr[r] += __shfl_xor(pr[r], off, 64);

    if (tx == 0) {
#pragma unroll
        for (int r = 0; r < 4; ++r) {
            int m = m0 + ty * 4 + r;
            if (m < n_t) atomicAdd(&yacc[sidx[ty * 4 + r]], pr[r]);
        }
    }
}

__global__ void fb_final(const float* __restrict__ yacc, const int* __restrict__ tv,
                         const float* __restrict__ b2, float* __restrict__ out) {
    int b = blockIdx.x * blockDim.x + threadIdx.x;
    if (b < B_N) {
        float x = yacc[b] + b2[tv[b]];
        out[b] = fmaxf(x, 0.f) + log1pf(expf(-fabsf(x)));
    }
}

extern "C" void kernel_launch(void* const* d_in, const int* in_sizes, int n_in,
                              void* d_out, int out_size, void* d_ws, size_t ws_size,
                              hipStream_t stream) {
    const float* g_exp = (const float*)d_in[0];
    const int*   tv    = (const int*)d_in[1];
    const float* W1    = (const float*)d_in[2];
    const float* b1    = (const float*)d_in[3];
    const float* W2    = (const float*)d_in[4];
    const float* b2    = (const float*)d_in[5];
    float* out = (float*)d_out;

    char* ws = (char*)d_ws;

    if (ws_size >= (size_t)WS_REQ) {
        int* cnt    = (int*)(ws + WS_CNT);
        int* offs   = (int*)(ws + WS_OFFS);
        int* order  = (int*)(ws + WS_ORDER);
        float* yacc8 = (float*)(ws + WS_YACC8);
        unsigned short* gA = (unsigned short*)(ws + WS_GA);
        k_prep_cvt<<<2049, 256, 0, stream>>>(g_exp, gA, tv, offs, order, cnt);
        k_gemm_mfma<<<512, 512, 0, stream>>>(gA, W1, offs, order, b1, W2,
                                             yacc8, cnt, tv, b2, out);
    } else {
        int* offs   = (int*)(ws + WS_OFFS);
        int* rank   = (int*)(ws + WS_RANK);
        int* order  = (int*)(ws + WS_ORDER);
        float* yacc = (float*)(ws + WS_YACC);
        k_prep_sb<<<1, 256, 0, stream>>>(tv, offs, rank, order, yacc);
        fb_gemm<<<dim3(4, 8, 32), 256, 0, stream>>>(g_exp, W1, b1, W2, offs, order, yacc);
        fb_final<<<32, 256, 0, stream>>>(yacc, tv, b2, out);
    }
}

// Round 7
// 118.464 us; speedup vs baseline: 1.7377x; 1.7377x over previous
//
#include <hip/hip_runtime.h>
#include <hip/hip_bf16.h>
#include <math.h>

#define B_N 8192
#define E_N 512
#define T_N 32

typedef short bf16x8 __attribute__((ext_vector_type(8)));
typedef float f32x4 __attribute__((ext_vector_type(4)));

// ---------------- ws layout (bytes) ----------------
#define WS_OFFS   256      // offs[33] (both paths)
#define WS_RANK   512      // fallback
#define WS_ORDER  33280    // order[8192] (both paths)
#define WS_YACC   66048    // fallback
#define WS_YACC8  98816    // main: 8 x 8192 floats (256 KB), slab = nt
#define WS_GA     (WS_YACC8 + 8 * B_N * 4)          // bf16 g_exp copy (8.4 MB)
#define WS_GW     (WS_GA + (size_t)B_N * E_N * 2)   // bf16 W1T (16.8 MB)
#define WS_REQ    (WS_GW + (size_t)T_N * E_N * E_N * 2)

typedef __attribute__((address_space(1))) const unsigned int gas_u32;
typedef __attribute__((address_space(3))) unsigned int las_u32;

// packed f32x2 -> bf16x2 (RNE)
static __device__ __forceinline__ unsigned int pk2(float a, float b) {
    __hip_bfloat162 h = __float22bfloat162_rn(float2{a, b});
    unsigned int u;
    __builtin_memcpy(&u, &h, 4);
    return u;
}

// ---- prep: blocks 0..2047 cvt g_exp f32->bf16; 2048..3071 transform W1
// (tiled transpose f32 [t][k][n] -> bf16 W1T [t][n][k], per-(t,64n)-slice
// DENSE 64KB, 16B k-chunks pre-XOR-swizzled pos = kc^(n&7)); block 3072
// builds the tissue counting-sort once.
// v13 post-mortem: the gemm's 35-44us floor was the B-prologue reading
// 256B strips of 2KB W1 rows (strided DRAM, ~30% eff, ~20-30us/CU).
// W1T makes every gemm block stream a dense contiguous 64KB bf16 slice.
__global__ __launch_bounds__(256) void k_prep_cvt(
    const float* __restrict__ g_exp, unsigned short* __restrict__ gA,
    const float* __restrict__ W1, unsigned short* __restrict__ W1T,
    const int* __restrict__ tv, int* __restrict__ offs_g,
    int* __restrict__ order) {
    int blk = blockIdx.x;
    int tid = threadIdx.x;
    if (blk < 2048) {  // ---- cvt A: 8 floats per thread ----
        int i = blk * 256 + tid;
        const f32x4* src = (const f32x4*)g_exp + (size_t)i * 2;
        f32x4 a = src[0], b = src[1];
        unsigned int uu[4] = {pk2(a[0], a[1]), pk2(a[2], a[3]),
                              pk2(b[0], b[1]), pk2(b[2], b[3])};
        int4 v;
        __builtin_memcpy(&v, uu, 16);
        *(int4*)(gA + (size_t)i * 8) = v;
        return;
    }
    if (blk < 3072) {  // ---- W1 transform: (t, 64n, 128k) tile ----
        int idx = blk - 2048;              // 0..1023
        int t = idx & 31, nb = (idx >> 5) & 7, kb = idx >> 8;
        __shared__ float Ts[128][68];      // pitch 68: 16B-aligned rows
        const float* src = W1 + ((size_t)t * E_N + kb * 128) * E_N + nb * 64;
        int f4 = tid & 15, r0 = tid >> 4;  // 16 rows per pass, 8 passes
#pragma unroll
        for (int p = 0; p < 8; ++p) {
            int r = r0 + p * 16;
            float4 v = *(const float4*)(src + (size_t)r * E_N + f4 * 4);
            *(float4*)&Ts[r][f4 * 4] = v;
        }
        __syncthreads();
        int n = tid & 63, kg = tid >> 6;   // kg 0..3 (32 k each)
        int kk0 = kg * 32;
        unsigned int u[16];
#pragma unroll
        for (int j = 0; j < 16; ++j)
            u[j] = pk2(Ts[kk0 + 2 * j][n], Ts[kk0 + 2 * j + 1][n]);
        unsigned short* dst = W1T + ((size_t)t * 512 + nb * 64 + n) * 512;
#pragma unroll
        for (int cj = 0; cj < 4; ++cj) {
            int kc = kb * 16 + kg * 4 + cj;      // global k-chunk (k/8)
            int pos = kc ^ (n & 7);              // pre-swizzled position
            int4 vv;
            __builtin_memcpy(&vv, &u[cj * 4], 16);
            *(int4*)(dst + pos * 8) = vv;
        }
        return;
    }
    // ---- single-block counting sort (proven structure) ----
    __shared__ int lh[4][32], wcur[4][32], offs_s[33];
    int w = tid >> 6;
    if (tid < 128) lh[tid >> 5][tid & 31] = 0;
    __syncthreads();
    int tval[32];
#pragma unroll
    for (int c = 0; c < 32; ++c) tval[c] = tv[c * 256 + tid];
#pragma unroll
    for (int c = 0; c < 32; ++c) atomicAdd(&lh[w][tval[c]], 1);
    __syncthreads();
    if (tid < 32) {
        int s = lh[0][tid] + lh[1][tid] + lh[2][tid] + lh[3][tid];
        int excl = 0;
#pragma unroll
        for (int i = 0; i < 32; ++i) {
            int v = __shfl(s, i, 64);
            if (i < tid) excl += v;
        }
        offs_s[tid] = excl;
        offs_g[tid] = excl;
        if (tid == 31) { offs_s[32] = excl + s; offs_g[32] = excl + s; }
    }
    __syncthreads();
    if (tid < 128) {
        int ww = tid >> 5, t = tid & 31;
        int s = offs_s[t];
        for (int w2 = 0; w2 < ww; ++w2) s += lh[w2][t];
        wcur[ww][t] = s;
    }
    __syncthreads();
#pragma unroll
    for (int c = 0; c < 32; ++c) {
        int b = c * 256 + tid;
        int pos = atomicAdd(&wcur[w][tval[c]], 1);
        order[pos] = b;
    }
}

// ---------- fused GEMM v14: (tissue, 64-col slice, row-half) blocks.
// B-prologue = 8 global_load_lds DMAs/thread of the DENSE pre-swizzled
// 64KB W1T slice (zero VALU, zero pack, perfectly coalesced, half bytes).
// Main loop: bf16 A global->VGPR depth-4 named ring (proven), B via
// ds_read_b128 with matching XOR (2-way bank alias = free). Sort hoisted
// to prep; final reduction back in its own dispatch (v13's threadfence
// fused-final caused 512 L2 flushes -> 3x regression; reverted).
// wi%8 == t%8: a tissue's 16 blocks on one XCD (L2 dedup of W1T + A rows).
__global__ __launch_bounds__(512, 4) void k_gemm_mfma(
    const unsigned short* __restrict__ gA, const unsigned short* __restrict__ W1T,
    const int* __restrict__ offs, const int* __restrict__ order,
    const float* __restrict__ b1, const float* __restrict__ W2,
    float* __restrict__ yacc8) {
    int wi = blockIdx.x;
    int t = wi & 31, nt = (wi >> 5) & 7, h = wi >> 8;
    int n0 = nt * 64;

    int tid = threadIdx.x;
    int w = tid >> 6, lane = tid & 63;
    int quad = (lane >> 4) & 3, l15 = lane & 15, l7 = lane & 7;

    __shared__ __align__(16) unsigned short Bs[64 * 512];  // 64 KB, linear

    // ---- B prologue: pure DMA of the dense pre-swizzled slice ----
    const unsigned short* Wsl = W1T + ((size_t)t * 512 + nt * 64) * 512;
#pragma unroll
    for (int i = 0; i < 8; ++i) {
        int c = i * 512 + tid;  // 16B chunk index (0..4095)
        __builtin_amdgcn_global_load_lds((gas_u32*)(Wsl + c * 8),
                                         (las_u32*)&Bs[c * 8], 16, 0, 0);
    }

    // scalar/epilogue constants overlap the DMA latency
    int base = offs[t];
    int n_t = offs[t + 1] - base;
    float b1v[4], w2v[4];
#pragma unroll
    for (int ni = 0; ni < 4; ++ni) {
        int n = t * E_N + n0 + ni * 16 + l15;
        b1v[ni] = b1[n];
        w2v[ni] = W2[n];
    }

    asm volatile("s_waitcnt vmcnt(0)" ::: "memory");
    __syncthreads();  // Bs final -- the ONLY barrier

    int MCn = (n_t + 127) >> 7;        // 128-row chunks for this tissue
    int MC = (MCn + 1 - h) >> 1;       // chunks of parity h owned here

    float* slab = yacc8 + (size_t)nt * B_N;

    for (int mc = 0; mc < MC; ++mc) {
        int ridx = (2 * mc + h) * 128 + w * 16 + l15;
        int row = order[base + (ridx < n_t ? ridx : 0)];
        const bf16x8* pAb = (const bf16x8*)(gA + (size_t)row * E_N) + quad;

        f32x4 acc[4];
#pragma unroll
        for (int ni = 0; ni < 4; ++ni) acc[ni] = (f32x4){0.f, 0.f, 0.f, 0.f};

        // depth-4 ring: named buffers, no register copies
        bf16x8 A0 = pAb[0], A1 = pAb[4], A2 = pAb[8], A3 = pAb[12];

#define KSTEP(S, ks) do {                                                                   \
        bf16x8 af = A##S;                                                                   \
        if (k4 < 3) A##S = pAb[((ks) + 4) * 4];                                             \
        int cx = (((ks) * 4 + quad) ^ l7) * 8;  /* swizzled k-chunk (shorts) */             \
        _Pragma("unroll") for (int ni = 0; ni < 4; ++ni) {                                  \
            bf16x8 bfr = *(const bf16x8*)(Bs + (ni * 16 + l15) * 512 + cx);                 \
            acc[ni] = __builtin_amdgcn_mfma_f32_16x16x32_bf16(af, bfr, acc[ni], 0, 0, 0);   \
        }                                                                                   \
    } while (0)

#pragma unroll 1
        for (int k4 = 0; k4 < 4; ++k4) {
            int ksb = k4 * 4;
            KSTEP(0, ksb + 0);
            KSTEP(1, ksb + 1);
            KSTEP(2, ksb + 2);
            KSTEP(3, ksb + 3);
        }
#undef KSTEP

        // epilogue: gelu(acc + b1) * W2, dot over this block's 64 cols
        float pr[4] = {0.f, 0.f, 0.f, 0.f};
#pragma unroll
        for (int ni = 0; ni < 4; ++ni) {
#pragma unroll
            for (int r = 0; r < 4; ++r) {
                float u = acc[ni][r] + b1v[ni];
                float gg = 0.5f * u * (1.f + erff(u * 0.70710678118654752f));
                pr[r] = fmaf(gg, w2v[ni], pr[r]);
            }
        }
#pragma unroll
        for (int off = 1; off <= 8; off <<= 1)
#pragma unroll
            for (int r = 0; r < 4; ++r) pr[r] += __shfl_xor(pr[r], off, 64);

        if (l15 == 0) {
#pragma unroll
            for (int r = 0; r < 4; ++r) {
                int rr = (2 * mc + h) * 128 + w * 16 + quad * 4 + r;  // global rank
                if (rr < n_t) slab[order[base + rr]] = pr[r];
            }
        }
    }
}

__global__ void k_final8(const float* __restrict__ yacc8, const int* __restrict__ tv,
                         const float* __restrict__ b2, float* __restrict__ out) {
    int b = blockIdx.x * blockDim.x + threadIdx.x;
    if (b < B_N) {
        float x = b2[tv[b]];
#pragma unroll
        for (int s = 0; s < 8; ++s) x += yacc8[(size_t)s * B_N + b];
        out[b] = fmaxf(x, 0.f) + log1pf(expf(-fabsf(x)));  // stable softplus
    }
}

// ================= fallback (fp32 path, proven) =================
__global__ __launch_bounds__(256) void k_prep_sb(
    const int* __restrict__ tv, int* __restrict__ offs_g,
    int* __restrict__ rank, int* __restrict__ order, float* __restrict__ yacc) {
    __shared__ int lh[4][32], wcur[4][32], offs_s[33];
    int tid = threadIdx.x, w = tid >> 6;
    if (tid < 128) lh[tid >> 5][tid & 31] = 0;
    __syncthreads();
    int tval[32];
#pragma unroll
    for (int c = 0; c < 32; ++c) tval[c] = tv[c * 256 + tid];
#pragma unroll
    for (int c = 0; c < 32; ++c) atomicAdd(&lh[w][tval[c]], 1);
    __syncthreads();
    if (tid < 32) {
        int s = lh[0][tid] + lh[1][tid] + lh[2][tid] + lh[3][tid];
        int excl = 0;
#pragma unroll
        for (int i = 0; i < 32; ++i) {
            int v = __shfl(s, i, 64);
            if (i < tid) excl += v;
        }
        offs_s[tid] = excl;
        offs_g[tid] = excl;
        if (tid == 31) { offs_s[32] = excl + s; offs_g[32] = excl + s; }
    }
    __syncthreads();
    if (tid < 128) {
        int ww = tid >> 5, t = tid & 31;
        int s = offs_s[t];
        for (int w2 = 0; w2 < ww; ++w2) s += lh[w2][t];
        wcur[ww][t] = s;
    }
    __syncthreads();
#pragma unroll
    for (int c = 0; c < 32; ++c) {
        int b = c * 256 + tid;
        int pos = atomicAdd(&wcur[w][tval[c]], 1);
        rank[b] = pos;
        order[pos] = b;
    }
    float4 z = make_float4(0.f, 0.f, 0.f, 0.f);
#pragma unroll
    for (int c = 0; c < 8; ++c) *(float4*)(yacc + (c * 256 + tid) * 4) = z;
}

__global__ __launch_bounds__(256) void fb_gemm(
    const float* __restrict__ g_exp, const float* __restrict__ W1,
    const float* __restrict__ b1, const float* __restrict__ W2,
    const int* __restrict__ offs, const int* __restrict__ order,
    float* __restrict__ yacc) {
    int t = blockIdx.z;
    int base = offs[t];
    int n_t = offs[t + 1] - base;
    int m0 = blockIdx.y * 64;
    if (m0 >= n_t) return;
    int n0 = blockIdx.x * 128;

    __shared__ float As2[32][68];
    __shared__ float Bs2[32][128];
    __shared__ int sidx[64];

    int tid = threadIdx.x;
    if (tid < 64) {
        int m = m0 + tid;
        sidx[tid] = (m < n_t) ? order[base + m] : -1;
    }
    __syncthreads();

    int ty = tid >> 4, tx = tid & 15;
    float acc[4][8];
#pragma unroll
    for (int r = 0; r < 4; ++r)
#pragma unroll
        for (int c = 0; c < 8; ++c) acc[r][c] = 0.f;

    for (int k0 = 0; k0 < E_N; k0 += 32) {
#pragma unroll
        for (int p = 0; p < 2; ++p) {
            int idx = tid + 256 * p;
            int row = idx >> 3, kcq = idx & 7;
            int s = sidx[row];
            float4 v = make_float4(0.f, 0.f, 0.f, 0.f);
            if (s >= 0) v = *(const float4*)(g_exp + (size_t)s * E_N + k0 + kcq * 4);
            As2[kcq * 4 + 0][row] = v.x;
            As2[kcq * 4 + 1][row] = v.y;
            As2[kcq * 4 + 2][row] = v.z;
            As2[kcq * 4 + 3][row] = v.w;
        }
#pragma unroll
        for (int p = 0; p < 4; ++p) {
            int idx = tid + 256 * p;
            int kr = idx >> 5, c4 = idx & 31;
            *(float4*)(&Bs2[kr][c4 * 4]) =
                *(const float4*)(W1 + ((size_t)t * E_N + (k0 + kr)) * E_N + n0 + c4 * 4);
        }
        __syncthreads();
#pragma unroll
        for (int e = 0; e < 32; ++e) {
            float4 a = *(const float4*)(&As2[e][ty * 4]);
            float4 bA = *(const float4*)(&Bs2[e][tx * 4]);
            float4 bB = *(const float4*)(&Bs2[e][tx * 4 + 64]);
            float av[4] = {a.x, a.y, a.z, a.w};
            float bv[8] = {bA.x, bA.y, bA.z, bA.w, bB.x, bB.y, bB.z, bB.w};
#pragma unroll
            for (int r = 0; r < 4; ++r)
#pragma unroll
                for (int c = 0; c < 8; ++c) acc[r][c] = fmaf(av[r], bv[c], acc[r][c]);
        }
        __syncthreads();
    }

    float pr[4] = {0.f, 0.f, 0.f, 0.f};
#pragma unroll
    for (int c = 0; c < 8; ++c) {
        int n = n0 + tx * 4 + ((c >= 4) ? 64 : 0) + (c & 3);
        float bb = b1[t * E_N + n];
        float w2 = W2[t * E_N + n];
#pragma unroll
        for (int r = 0; r < 4; ++r) {
            float u = acc[r][c] + bb;
            float g = 0.5f * u * (1.f + erff(u * 0.70710678118654752f));
            pr[r] = fmaf(g, w2, pr[r]);
        }
    }
#pragma unroll
    for (int off = 8; off >= 1; off >>= 1)
#pragma unroll
        for (int r = 0; r < 4; ++r) pr[r] += __shfl_xor(pr[r], off, 64);

    if (tx == 0) {
#pragma unroll
        for (int r = 0; r < 4; ++r) {
            int m = m0 + ty * 4 + r;
            if (m < n_t) atomicAdd(&yacc[sidx[ty * 4 + r]], pr[r]);
        }
    }
}

__global__ void fb_final(const float* __restrict__ yacc, const int* __restrict__ tv,
                         const float* __restrict__ b2, float* __restrict__ out) {
    int b = blockIdx.x * blockDim.x + threadIdx.x;
    if (b < B_N) {
        float x = yacc[b] + b2[tv[b]];
        out[b] = fmaxf(x, 0.f) + log1pf(expf(-fabsf(x)));
    }
}

extern "C" void kernel_launch(void* const* d_in, const int* in_sizes, int n_in,
                              void* d_out, int out_size, void* d_ws, size_t ws_size,
                              hipStream_t stream) {
    const float* g_exp = (const float*)d_in[0];
    const int*   tv    = (const int*)d_in[1];
    const float* W1    = (const float*)d_in[2];
    const float* b1    = (const float*)d_in[3];
    const float* W2    = (const float*)d_in[4];
    const float* b2    = (const float*)d_in[5];
    float* out = (float*)d_out;

    char* ws = (char*)d_ws;

    if (ws_size >= (size_t)WS_REQ) {
        int* offs    = (int*)(ws + WS_OFFS);
        int* order   = (int*)(ws + WS_ORDER);
        float* yacc8 = (float*)(ws + WS_YACC8);
        unsigned short* gA  = (unsigned short*)(ws + WS_GA);
        unsigned short* W1T = (unsigned short*)(ws + WS_GW);
        k_prep_cvt<<<3073, 256, 0, stream>>>(g_exp, gA, W1, W1T, tv, offs, order);
        k_gemm_mfma<<<512, 512, 0, stream>>>(gA, W1T, offs, order, b1, W2, yacc8);
        k_final8<<<32, 256, 0, stream>>>(yacc8, tv, b2, out);
    } else {
        int* offs   = (int*)(ws + WS_OFFS);
        int* rank   = (int*)(ws + WS_RANK);
        int* order  = (int*)(ws + WS_ORDER);
        float* yacc = (float*)(ws + WS_YACC);
        k_prep_sb<<<1, 256, 0, stream>>>(tv, offs, rank, order, yacc);
        fb_gemm<<<dim3(4, 8, 32), 256, 0, stream>>>(g_exp, W1, b1, W2, offs, order, yacc);
        fb_final<<<32, 256, 0, stream>>>(yacc, tv, b2, out);
    }
}

// Round 8
// 112.466 us; speedup vs baseline: 1.8304x; 1.0533x over previous
//
#include <hip/hip_runtime.h>
#include <hip/hip_bf16.h>
#include <math.h>

#define B_N 8192
#define E_N 512
#define T_N 32
#define BP 520  // B LDS pitch in shorts (1040 B, 16B-aligned rows)

typedef short bf16x8 __attribute__((ext_vector_type(8)));
typedef float f32x4 __attribute__((ext_vector_type(4)));

// ---------------- ws layout (bytes) ----------------
#define WS_OFFS   256      // offs[33] (both paths)
#define WS_RANK   512      // fallback
#define WS_ORDER  33280    // order[8192] (both paths)
#define WS_YACC   66048    // fallback
#define WS_YACC8  98816    // main: 8 x 8192 floats (256 KB), slab = nt
#define WS_GA     (WS_YACC8 + 8 * B_N * 4)          // bf16 g_exp copy (8.4 MB)
#define WS_REQ    (WS_GA + (size_t)B_N * E_N * 2)

// packed f32x2 -> bf16x2 (RNE)
static __device__ __forceinline__ unsigned int pk2(float a, float b) {
    __hip_bfloat162 h = __float22bfloat162_rn(float2{a, b});
    unsigned int u;
    __builtin_memcpy(&u, &h, 4);
    return u;
}

// ---- prep: blocks 0..2047 cvt g_exp f32->bf16 (v9's exact cvt);
// block 2048 builds the tissue counting-sort (offs/order) once.
// v14 post-mortem: W1 is L3-resident across iterations (FETCH ~25MB,
// not 134MB) and 256B strips are whole cache lines -- the "strided DRAM"
// theory was wrong; layout transforms add passes for nothing. v15 =
// best-measured config (v9, 111.0us) + the two individually-verified
// deltas: sort hoisted out of the gemm (v13-proven order[] indexing),
// lower-conflict B swizzle (v10/v11).
__global__ __launch_bounds__(256) void k_prep_cvt(
    const float* __restrict__ g_exp, unsigned short* __restrict__ gA,
    const int* __restrict__ tv, int* __restrict__ offs_g,
    int* __restrict__ order) {
    int blk = blockIdx.x;
    int tid = threadIdx.x;
    if (blk < 2048) {  // ---- cvt A: 8 floats per thread ----
        int i = blk * 256 + tid;
        const f32x4* src = (const f32x4*)g_exp + (size_t)i * 2;
        f32x4 a = src[0], b = src[1];
        unsigned int uu[4] = {pk2(a[0], a[1]), pk2(a[2], a[3]),
                              pk2(b[0], b[1]), pk2(b[2], b[3])};
        int4 v;
        __builtin_memcpy(&v, uu, 16);
        *(int4*)(gA + (size_t)i * 8) = v;
        return;
    }
    // ---- single-block counting sort (proven structure) ----
    __shared__ int lh[4][32], wcur[4][32], offs_s[33];
    int w = tid >> 6;
    if (tid < 128) lh[tid >> 5][tid & 31] = 0;
    __syncthreads();
    int tval[32];
#pragma unroll
    for (int c = 0; c < 32; ++c) tval[c] = tv[c * 256 + tid];
#pragma unroll
    for (int c = 0; c < 32; ++c) atomicAdd(&lh[w][tval[c]], 1);
    __syncthreads();
    if (tid < 32) {
        int s = lh[0][tid] + lh[1][tid] + lh[2][tid] + lh[3][tid];
        int excl = 0;
#pragma unroll
        for (int i = 0; i < 32; ++i) {
            int v = __shfl(s, i, 64);
            if (i < tid) excl += v;
        }
        offs_s[tid] = excl;
        offs_g[tid] = excl;
        if (tid == 31) { offs_s[32] = excl + s; offs_g[32] = excl + s; }
    }
    __syncthreads();
    if (tid < 128) {
        int ww = tid >> 5, t = tid & 31;
        int s = offs_s[t];
        for (int w2 = 0; w2 < ww; ++w2) s += lh[w2][t];
        wcur[ww][t] = s;
    }
    __syncthreads();
#pragma unroll
    for (int c = 0; c < 32; ++c) {
        int b = c * 256 + tid;
        int pos = atomicAdd(&wcur[w][tval[c]], 1);
        order[pos] = b;
    }
}

// ---------- fused GEMM v15: (tissue, 64-col slice, row-half) blocks.
// = v9's verified compute core (bf16 A global->VGPR, no main-loop
// barriers, 2 blocks/CU, wi%8==t%8 XCD affinity) with the per-block
// counting sort replaced by order[]/offs[] reads (built once in prep)
// and the v10/v11 B-swizzle (1.59M vs 2.9M bank-conflict cycles).
__global__ __launch_bounds__(512, 4) void k_gemm_mfma(
    const unsigned short* __restrict__ gA, const float* __restrict__ W1,
    const int* __restrict__ offs, const int* __restrict__ order,
    const float* __restrict__ b1, const float* __restrict__ W2,
    float* __restrict__ yacc8) {
    int wi = blockIdx.x;
    int t = wi & 31, nt = (wi >> 5) & 7, h = wi >> 8;
    int n0 = nt * 64;

    int tid = threadIdx.x;
    int w = tid >> 6, lane = tid & 63;
    int quad = (lane >> 4) & 3, l15 = lane & 15;

    __shared__ __align__(16) unsigned short Bs[64 * BP];  // 66560 B

    int base = offs[t];
    int n_t = offs[t + 1] - base;

    // per-lane epilogue constants (cols n0 + ni*16 + l15)
    float b1v[4], w2v[4];
#pragma unroll
    for (int ni = 0; ni < 4; ++ni) {
        int n = t * E_N + n0 + ni * 16 + l15;
        b1v[ni] = b1[n];
        w2v[ni] = W2[n];
    }

    // ---- B prologue: W1[t][k][n0:n0+64] fp32 -> Bs[n][k] bf16 (k-major,
    // packed pairs, word idx XOR-swizzled). Two-phase x2: batch 4 iters'
    // loads (8 in flight), then pack+write.
    const float* Wsrc = W1 + (size_t)t * E_N * E_N + n0;
    unsigned int* Bw = (unsigned int*)Bs;  // word idx = n*260 + swz(k2)
#pragma unroll 1
    for (int g = 0; g < 2; ++g) {
        float4 va[4], vb[4];
#pragma unroll
        for (int i = 0; i < 4; ++i) {
            int flat = (g * 4 + i) * 512 + tid;  // 0..4095
            int k2 = flat >> 4, nq = flat & 15;
            va[i] = *(const float4*)(Wsrc + (size_t)(2 * k2) * E_N + nq * 4);
            vb[i] = *(const float4*)(Wsrc + (size_t)(2 * k2 + 1) * E_N + nq * 4);
        }
#pragma unroll
        for (int i = 0; i < 4; ++i) {
            int flat = (g * 4 + i) * 512 + tid;
            int k2 = flat >> 4, nq = flat & 15;
            int k2s = k2 ^ ((nq & 7) << 2);  // matches read swizzle ((n>>2)&7)<<2
            Bw[(nq * 4 + 0) * 260 + k2s] = pk2(va[i].x, vb[i].x);
            Bw[(nq * 4 + 1) * 260 + k2s] = pk2(va[i].y, vb[i].y);
            Bw[(nq * 4 + 2) * 260 + k2s] = pk2(va[i].z, vb[i].z);
            Bw[(nq * 4 + 3) * 260 + k2s] = pk2(va[i].w, vb[i].w);
        }
    }
    __syncthreads();  // Bs final -- the ONLY barrier

    int MCn = (n_t + 127) >> 7;        // 128-row chunks for this tissue
    int MC = (MCn + 1 - h) >> 1;       // chunks of parity h owned here

    float* slab = yacc8 + (size_t)nt * B_N;

    for (int mc = 0; mc < MC; ++mc) {
        // lane (quad,l15): A-frag = 8 consecutive bf16 k-values of its row
        int ridx = (2 * mc + h) * 128 + w * 16 + l15;
        int row = order[base + (ridx < n_t ? ridx : 0)];
        const bf16x8* pAb = (const bf16x8*)(gA + (size_t)row * E_N) + quad;

        f32x4 acc[4];
#pragma unroll
        for (int ni = 0; ni < 4; ++ni) acc[ni] = (f32x4){0.f, 0.f, 0.f, 0.f};

        // depth-4 ring: named buffers, no register copies
        bf16x8 A0 = pAb[0], A1 = pAb[4], A2 = pAb[8], A3 = pAb[12];

#define KSTEP(S, ks) do {                                                                   \
        bf16x8 af = A##S;                                                                   \
        if (k4 < 3) A##S = pAb[((ks) + 4) * 4];                                             \
        _Pragma("unroll") for (int ni = 0; ni < 4; ++ni) {                                  \
            int bswz = ((ni * 4 + (l15 >> 2)) & 7) << 3;  /* read-side XOR (shorts) */      \
            bf16x8 bfr = *(const bf16x8*)(Bs + (ni * 16 + l15) * BP +                       \
                                          (((ks) * 32 + quad * 8) ^ bswz));                 \
            acc[ni] = __builtin_amdgcn_mfma_f32_16x16x32_bf16(af, bfr, acc[ni], 0, 0, 0);   \
        }                                                                                   \
    } while (0)

#pragma unroll 1
        for (int k4 = 0; k4 < 4; ++k4) {
            int ksb = k4 * 4;
            KSTEP(0, ksb + 0);
            KSTEP(1, ksb + 1);
            KSTEP(2, ksb + 2);
            KSTEP(3, ksb + 3);
        }
#undef KSTEP

        // epilogue: gelu(acc + b1) * W2, dot over this block's 64 cols
        float pr[4] = {0.f, 0.f, 0.f, 0.f};
#pragma unroll
        for (int ni = 0; ni < 4; ++ni) {
#pragma unroll
            for (int r = 0; r < 4; ++r) {
                float u = acc[ni][r] + b1v[ni];
                float gg = 0.5f * u * (1.f + erff(u * 0.70710678118654752f));
                pr[r] = fmaf(gg, w2v[ni], pr[r]);
            }
        }
#pragma unroll
        for (int off = 1; off <= 8; off <<= 1)
#pragma unroll
            for (int r = 0; r < 4; ++r) pr[r] += __shfl_xor(pr[r], off, 64);

        if (l15 == 0) {
#pragma unroll
            for (int r = 0; r < 4; ++r) {
                int rr = (2 * mc + h) * 128 + w * 16 + quad * 4 + r;  // global rank
                if (rr < n_t) slab[order[base + rr]] = pr[r];
            }
        }
    }
}

__global__ void k_final8(const float* __restrict__ yacc8, const int* __restrict__ tv,
                         const float* __restrict__ b2, float* __restrict__ out) {
    int b = blockIdx.x * blockDim.x + threadIdx.x;
    if (b < B_N) {
        float x = b2[tv[b]];
#pragma unroll
        for (int s = 0; s < 8; ++s) x += yacc8[(size_t)s * B_N + b];
        out[b] = fmaxf(x, 0.f) + log1pf(expf(-fabsf(x)));  // stable softplus
    }
}

// ================= fallback (fp32 path, proven) =================
__global__ __launch_bounds__(256) void k_prep_sb(
    const int* __restrict__ tv, int* __restrict__ offs_g,
    int* __restrict__ rank, int* __restrict__ order, float* __restrict__ yacc) {
    __shared__ int lh[4][32], wcur[4][32], offs_s[33];
    int tid = threadIdx.x, w = tid >> 6;
    if (tid < 128) lh[tid >> 5][tid & 31] = 0;
    __syncthreads();
    int tval[32];
#pragma unroll
    for (int c = 0; c < 32; ++c) tval[c] = tv[c * 256 + tid];
#pragma unroll
    for (int c = 0; c < 32; ++c) atomicAdd(&lh[w][tval[c]], 1);
    __syncthreads();
    if (tid < 32) {
        int s = lh[0][tid] + lh[1][tid] + lh[2][tid] + lh[3][tid];
        int excl = 0;
#pragma unroll
        for (int i = 0; i < 32; ++i) {
            int v = __shfl(s, i, 64);
            if (i < tid) excl += v;
        }
        offs_s[tid] = excl;
        offs_g[tid] = excl;
        if (tid == 31) { offs_s[32] = excl + s; offs_g[32] = excl + s; }
    }
    __syncthreads();
    if (tid < 128) {
        int ww = tid >> 5, t = tid & 31;
        int s = offs_s[t];
        for (int w2 = 0; w2 < ww; ++w2) s += lh[w2][t];
        wcur[ww][t] = s;
    }
    __syncthreads();
#pragma unroll
    for (int c = 0; c < 32; ++c) {
        int b = c * 256 + tid;
        int pos = atomicAdd(&wcur[w][tval[c]], 1);
        rank[b] = pos;
        order[pos] = b;
    }
    float4 z = make_float4(0.f, 0.f, 0.f, 0.f);
#pragma unroll
    for (int c = 0; c < 8; ++c) *(float4*)(yacc + (c * 256 + tid) * 4) = z;
}

__global__ __launch_bounds__(256) void fb_gemm(
    const float* __restrict__ g_exp, const float* __restrict__ W1,
    const float* __restrict__ b1, const float* __restrict__ W2,
    const int* __restrict__ offs, const int* __restrict__ order,
    float* __restrict__ yacc) {
    int t = blockIdx.z;
    int base = offs[t];
    int n_t = offs[t + 1] - base;
    int m0 = blockIdx.y * 64;
    if (m0 >= n_t) return;
    int n0 = blockIdx.x * 128;

    __shared__ float As2[32][68];
    __shared__ float Bs2[32][128];
    __shared__ int sidx[64];

    int tid = threadIdx.x;
    if (tid < 64) {
        int m = m0 + tid;
        sidx[tid] = (m < n_t) ? order[base + m] : -1;
    }
    __syncthreads();

    int ty = tid >> 4, tx = tid & 15;
    float acc[4][8];
#pragma unroll
    for (int r = 0; r < 4; ++r)
#pragma unroll
        for (int c = 0; c < 8; ++c) acc[r][c] = 0.f;

    for (int k0 = 0; k0 < E_N; k0 += 32) {
#pragma unroll
        for (int p = 0; p < 2; ++p) {
            int idx = tid + 256 * p;
            int row = idx >> 3, kcq = idx & 7;
            int s = sidx[row];
            float4 v = make_float4(0.f, 0.f, 0.f, 0.f);
            if (s >= 0) v = *(const float4*)(g_exp + (size_t)s * E_N + k0 + kcq * 4);
            As2[kcq * 4 + 0][row] = v.x;
            As2[kcq * 4 + 1][row] = v.y;
            As2[kcq * 4 + 2][row] = v.z;
            As2[kcq * 4 + 3][row] = v.w;
        }
#pragma unroll
        for (int p = 0; p < 4; ++p) {
            int idx = tid + 256 * p;
            int kr = idx >> 5, c4 = idx & 31;
            *(float4*)(&Bs2[kr][c4 * 4]) =
                *(const float4*)(W1 + ((size_t)t * E_N + (k0 + kr)) * E_N + n0 + c4 * 4);
        }
        __syncthreads();
#pragma unroll
        for (int e = 0; e < 32; ++e) {
            float4 a = *(const float4*)(&As2[e][ty * 4]);
            float4 bA = *(const float4*)(&Bs2[e][tx * 4]);
            float4 bB = *(const float4*)(&Bs2[e][tx * 4 + 64]);
            float av[4] = {a.x, a.y, a.z, a.w};
            float bv[8] = {bA.x, bA.y, bA.z, bA.w, bB.x, bB.y, bB.z, bB.w};
#pragma unroll
            for (int r = 0; r < 4; ++r)
#pragma unroll
                for (int c = 0; c < 8; ++c) acc[r][c] = fmaf(av[r], bv[c], acc[r][c]);
        }
        __syncthreads();
    }

    float pr[4] = {0.f, 0.f, 0.f, 0.f};
#pragma unroll
    for (int c = 0; c < 8; ++c) {
        int n = n0 + tx * 4 + ((c >= 4) ? 64 : 0) + (c & 3);
        float bb = b1[t * E_N + n];
        float w2 = W2[t * E_N + n];
#pragma unroll
        for (int r = 0; r < 4; ++r) {
            float u = acc[r][c] + bb;
            float g = 0.5f * u * (1.f + erff(u * 0.70710678118654752f));
            pr[r] = fmaf(g, w2, pr[r]);
        }
    }
#pragma unroll
    for (int off = 8; off >= 1; off >>= 1)
#pragma unroll
        for (int r = 0; r < 4; ++r) pr[r] += __shfl_xor(pr[r], off, 64);

    if (tx == 0) {
#pragma unroll
        for (int r = 0; r < 4; ++r) {
            int m = m0 + ty * 4 + r;
            if (m < n_t) atomicAdd(&yacc[sidx[ty * 4 + r]], pr[r]);
        }
    }
}

__global__ void fb_final(const float* __restrict__ yacc, const int* __restrict__ tv,
                         const float* __restrict__ b2, float* __restrict__ out) {
    int b = blockIdx.x * blockDim.x + threadIdx.x;
    if (b < B_N) {
        float x = yacc[b] + b2[tv[b]];
        out[b] = fmaxf(x, 0.f) + log1pf(expf(-fabsf(x)));
    }
}

extern "C" void kernel_launch(void* const* d_in, const int* in_sizes, int n_in,
                              void* d_out, int out_size, void* d_ws, size_t ws_size,
                              hipStream_t stream) {
    const float* g_exp = (const float*)d_in[0];
    const int*   tv    = (const int*)d_in[1];
    const float* W1    = (const float*)d_in[2];
    const float* b1    = (const float*)d_in[3];
    const float* W2    = (const float*)d_in[4];
    const float* b2    = (const float*)d_in[5];
    float* out = (float*)d_out;

    char* ws = (char*)d_ws;

    if (ws_size >= (size_t)WS_REQ) {
        int* offs    = (int*)(ws + WS_OFFS);
        int* order   = (int*)(ws + WS_ORDER);
        float* yacc8 = (float*)(ws + WS_YACC8);
        unsigned short* gA = (unsigned short*)(ws + WS_GA);
        k_prep_cvt<<<2049, 256, 0, stream>>>(g_exp, gA, tv, offs, order);
        k_gemm_mfma<<<512, 512, 0, stream>>>(gA, W1, offs, order, b1, W2, yacc8);
        k_final8<<<32, 256, 0, stream>>>(yacc8, tv, b2, out);
    } else {
        int* offs   = (int*)(ws + WS_OFFS);
        int* rank   = (int*)(ws + WS_RANK);
        int* order  = (int*)(ws + WS_ORDER);
        float* yacc = (float*)(ws + WS_YACC);
        k_prep_sb<<<1, 256, 0, stream>>>(tv, offs, rank, order, yacc);
        fb_gemm<<<dim3(4, 8, 32), 256, 0, stream>>>(g_exp, W1, b1, W2, offs, order, yacc);
        fb_final<<<32, 256, 0, stream>>>(yacc, tv, b2, out);
    }
}